// Round 2
// baseline (77816.077 us; speedup 1.0000x reference)
//
#include <hip/hip_runtime.h>
#include <hip/hip_bf16.h>

#define H    2048
#define LSEQ 512
#define NWG  256
#define TPB  256
#define UPW  8     // hidden units per WG (H/NWG)
#define RPW  32    // gate rows per WG (4*UPW)

// ws float layout: [0,512) ua | [512,2560) x | [2560,4608) h | ints at 4608: cnt, gen
#define WS_UA 0
#define WS_X  512
#define WS_H  2560
#define WS_I  4608

__device__ __forceinline__ float sigmoidf_(float v) { return 1.f / (1.f + __expf(-v)); }

__device__ __forceinline__ void grid_barrier(int* cnt, int* gen) {
  __syncthreads();
  __threadfence();  // release: make x/h writes visible device-wide
  if (threadIdx.x == 0) {
    int g = __hip_atomic_load(gen, __ATOMIC_RELAXED, __HIP_MEMORY_SCOPE_AGENT);
    int prev = __hip_atomic_fetch_add(cnt, 1, __ATOMIC_ACQ_REL, __HIP_MEMORY_SCOPE_AGENT);
    if (prev == NWG - 1) {
      __hip_atomic_store(cnt, 0, __ATOMIC_RELAXED, __HIP_MEMORY_SCOPE_AGENT);
      __hip_atomic_fetch_add(gen, 1, __ATOMIC_ACQ_REL, __HIP_MEMORY_SCOPE_AGENT);
    } else {
      while (__hip_atomic_load(gen, __ATOMIC_ACQUIRE, __HIP_MEMORY_SCOPE_AGENT) == g) {
        __builtin_amdgcn_s_sleep(8);
      }
    }
  }
  __syncthreads();
  __threadfence();  // acquire side for all lanes (cross-XCD L2)
}

__global__ void init_ws(float* ws) {
  int tid = threadIdx.x;
  for (int i = tid; i < H; i += 1024) ws[WS_H + i] = 0.f;  // h0 = 0
  if (tid == 0) { ((int*)(ws + WS_I))[0] = 0; ((int*)(ws + WS_I))[1] = 0; }
}

__global__ __launch_bounds__(TPB) void attn_rnn_main(
    const float* __restrict__ input, const float* __restrict__ bias_mat,
    const float* __restrict__ conv_w, const float* __restrict__ conv_b,
    const float* __restrict__ fc1_w, const float* __restrict__ fc1_b,
    const float* __restrict__ w_ih, const float* __restrict__ b_ih,
    const float* __restrict__ w_hh, const float* __restrict__ b_hh,
    const int* __restrict__ seq_len,
    float* __restrict__ out, float* __restrict__ ws)
{
  const int w    = blockIdx.x;
  const int tid  = threadIdx.x;
  const int lane = tid & 63;
  const int wave = tid >> 6;

  float* ua = ws + WS_UA;
  float* xg = ws + WS_X;
  float* hg = ws + WS_H;
  int*   cnt = (int*)(ws + WS_I);
  int*   gen = cnt + 1;

  __shared__ float h_lds[H];
  __shared__ float x_lds[H];
  __shared__ float attn_lds[LSEQ];
  __shared__ float ub_lds[LSEQ];     // step-invariant ua[l] + bias_mat[l]
  __shared__ float g_lds[RPW];
  __shared__ float red4[4];
  __shared__ float red48[4 * 8];
  __shared__ float sc[2];
  __shared__ float c_state[UPW];

  // row/k mapping: 32 rows x 8 k-groups per WG
  const int r_local = tid >> 3;           // 0..31
  const int kg      = tid & 7;            // 0..7
  const int gt      = r_local >> 3;       // gate type 0..3 (i,f,g,o)
  const int u       = r_local & 7;        // unit within WG
  const int rg      = gt * H + w * UPW + u;   // global gate row
  const float brow  = b_ih[rg] + b_hh[rg];
  const float4* wih_row = reinterpret_cast<const float4*>(w_ih + (size_t)rg * H);
  const float4* whh_row = reinterpret_cast<const float4*>(w_hh + (size_t)rg * H);

  if (tid < UPW) c_state[tid] = 0.f;

  // ---- precompute ua[l] = input[l,:]·conv_w + conv_b  (WG w owns l=2w,2w+1) ----
  const float cb = conv_b[0];
  for (int li = 0; li < 2; ++li) {
    int l = w * 2 + li;
    const float* row = input + (size_t)l * H;
    float s = 0.f;
    for (int i = tid; i < H; i += TPB) s += row[i] * conv_w[i];
    for (int m = 32; m; m >>= 1) s += __shfl_xor(s, m);
    if (lane == 0) red4[wave] = s;
    __syncthreads();
    if (tid == 0) ua[l] = red4[0] + red4[1] + red4[2] + red4[3] + cb;
    __syncthreads();
  }
  grid_barrier(cnt, gen);  // ua visible to all

  // hoist step-invariant logits base into LDS
  #pragma unroll
  for (int ii = 0; ii < 2; ++ii) {
    int l = tid + ii * 256;
    ub_lds[l] = ua[l] + bias_mat[l];
  }
  __syncthreads();

  const int S = seq_len[0];
  const float fb = fc1_b[0];

  for (int t = 0; t < S; ++t) {
    // ================= phase A (needs h_t) =================
    // copy h -> LDS, compute w_a = h·fc1_w + fc1_b (redundant per WG, deterministic)
    float s = 0.f;
    for (int i = tid; i < H; i += TPB) {
      float hv = hg[i];
      h_lds[i] = hv;
      s += hv * fc1_w[i];
    }
    for (int m = 32; m; m >>= 1) s += __shfl_xor(s, m);
    if (lane == 0) red4[wave] = s;
    __syncthreads();
    if (tid == 0) sc[0] = red4[0] + red4[1] + red4[2] + red4[3] + fb;
    __syncthreads();
    const float w_a = sc[0];

    // softmax over 512 logits (redundant per WG)
    // note: bias_mat added AFTER leaky_relu per reference
    float lg[2];
    float mx = -1e30f;
    #pragma unroll
    for (int ii = 0; ii < 2; ++ii) {
      int l = tid + ii * 256;
      float v0 = ua[l] + w_a;                 // ua from ws is L1-hot; leaky first
      float v = v0 > 0.f ? v0 : 0.01f * v0;   // leaky_relu slope 0.01
      v += ub_lds[l] - ua[l];                 // == bias_mat[l]
      lg[ii] = v;
      mx = fmaxf(mx, v);
    }
    for (int m = 32; m; m >>= 1) mx = fmaxf(mx, __shfl_xor(mx, m));
    if (lane == 0) red4[wave] = mx;
    __syncthreads();
    if (tid == 0) sc[0] = fmaxf(fmaxf(red4[0], red4[1]), fmaxf(red4[2], red4[3]));
    __syncthreads();
    mx = sc[0];
    float se = 0.f;
    #pragma unroll
    for (int ii = 0; ii < 2; ++ii) {
      int l = tid + ii * 256;
      float e = __expf(lg[ii] - mx);
      attn_lds[l] = e;
      se += e;
    }
    for (int m = 32; m; m >>= 1) se += __shfl_xor(se, m);
    if (lane == 0) red4[wave] = se;
    __syncthreads();
    if (tid == 0) sc[1] = 1.f / (red4[0] + red4[1] + red4[2] + red4[3]);
    __syncthreads();
    const float inv = sc[1];

    // x slice: this WG produces x[j0..j0+7]
    const int j0 = w * UPW;
    float p[8];
    #pragma unroll
    for (int jj = 0; jj < 8; ++jj) p[jj] = 0.f;
    #pragma unroll
    for (int ii = 0; ii < 2; ++ii) {
      int l = tid + ii * 256;
      float e = attn_lds[l];
      const float4* r4 = reinterpret_cast<const float4*>(input + (size_t)l * H + j0);
      float4 a = r4[0], b = r4[1];
      p[0] += e * a.x; p[1] += e * a.y; p[2] += e * a.z; p[3] += e * a.w;
      p[4] += e * b.x; p[5] += e * b.y; p[6] += e * b.z; p[7] += e * b.w;
    }
    #pragma unroll
    for (int jj = 0; jj < 8; ++jj) {
      float v = p[jj];
      for (int m = 32; m; m >>= 1) v += __shfl_xor(v, m);
      if (lane == 0) red48[wave * 8 + jj] = v;
    }
    __syncthreads();
    if (tid < 8) {
      float v = red48[tid] + red48[8 + tid] + red48[16 + tid] + red48[24 + tid];
      xg[j0 + tid] = v * inv;
    }

    // W_hh @ h partial (heavy, overlaps with other WGs finishing attention)
    float acc = 0.f;
    #pragma unroll 8
    for (int m = 0; m < 64; ++m) {
      float4 wv = whh_row[kg + 8 * m];
      int k = kg * 4 + 32 * m;
      acc += wv.x * h_lds[k] + wv.y * h_lds[k + 1] + wv.z * h_lds[k + 2] + wv.w * h_lds[k + 3];
    }

    grid_barrier(cnt, gen);  // x complete

    // ================= phase B (needs x) =================
    for (int i = tid; i < H; i += TPB) x_lds[i] = xg[i];
    __syncthreads();

    #pragma unroll 8
    for (int m = 0; m < 64; ++m) {
      float4 wv = wih_row[kg + 8 * m];
      int k = kg * 4 + 32 * m;
      acc += wv.x * x_lds[k] + wv.y * x_lds[k + 1] + wv.z * x_lds[k + 2] + wv.w * x_lds[k + 3];
    }
    // reduce across the 8 k-groups of each row (adjacent lanes)
    acc += __shfl_xor(acc, 1);
    acc += __shfl_xor(acc, 2);
    acc += __shfl_xor(acc, 4);
    if (kg == 0) g_lds[r_local] = acc + brow;
    __syncthreads();

    if (tid < UPW) {
      float iv = g_lds[0 * UPW + tid];
      float fv = g_lds[1 * UPW + tid];
      float gv = g_lds[2 * UPW + tid];
      float ov = g_lds[3 * UPW + tid];
      float c_new = sigmoidf_(fv) * c_state[tid] + sigmoidf_(iv) * tanhf(gv);
      float h_new = sigmoidf_(ov) * tanhf(c_new);
      c_state[tid] = c_new;
      int j = w * UPW + tid;
      hg[j] = h_new;
      out[(size_t)t * H + j] = h_new;
    }

    grid_barrier(cnt, gen);  // h complete for step t+1
  }
}

extern "C" void kernel_launch(void* const* d_in, const int* in_sizes, int n_in,
                              void* d_out, int out_size, void* d_ws, size_t ws_size,
                              hipStream_t stream) {
  const float* input    = (const float*)d_in[0];
  const float* bias_mat = (const float*)d_in[1];
  const float* conv_w   = (const float*)d_in[2];
  const float* conv_b   = (const float*)d_in[3];
  const float* fc1_w    = (const float*)d_in[4];
  const float* fc1_b    = (const float*)d_in[5];
  const float* w_ih     = (const float*)d_in[6];
  const float* b_ih     = (const float*)d_in[7];
  const float* w_hh     = (const float*)d_in[8];
  const float* b_hh     = (const float*)d_in[9];
  const int*   seqp     = (const int*)d_in[10];
  float* out = (float*)d_out;
  float* ws  = (float*)d_ws;

  hipLaunchKernelGGL(init_ws, dim3(1), dim3(1024), 0, stream, ws);
  hipLaunchKernelGGL(attn_rnn_main, dim3(NWG), dim3(TPB), 0, stream,
                     input, bias_mat, conv_w, conv_b, fc1_w, fc1_b,
                     w_ih, b_ih, w_hh, b_hh, seqp, out, ws);
}

// Round 3
// 46494.464 us; speedup vs baseline: 1.6737x; 1.6737x over previous
//
#include <hip/hip_runtime.h>
#include <hip/hip_bf16.h>

#define H     2048
#define LSEQ  512
#define NWG   256
#define TPB   512
#define UPW   8     // hidden units per WG
#define RPW   32    // gate rows per WG
#define KG    16    // k-groups per row

// ws float-index layout
#define WS_UA    0        // 512 floats
#define WS_X     512      // 2048 floats (fallback path only)
#define WS_H     2560     // 2048 floats
#define WS_GEN   4608     // 1 int
#define WS_FLAGS 4640     // 256*32 ints (128B-padded arrival flags)
#define WS_P     16384    // 8192*512 floats = 16 MB
#define WS_P_END (WS_P + 4 * H * LSEQ / 2)  // placeholder, computed below
#define WS_NEED_FLOATS (WS_P + (size_t)4 * H * LSEQ)
#define WS_NEED_BYTES  (WS_NEED_FLOATS * 4)

__device__ __forceinline__ float sigmoidf_(float v) { return 1.f / (1.f + __expf(-v)); }

// Flag-based grid barrier: parallel arrivals (one padded line per WG), WG0
// sweeps flags with 256 threads, then releases via monotone gen counter.
__device__ __forceinline__ void flag_barrier(int* flags, int* gen, int ep, int wg) {
  __syncthreads();
  __threadfence();  // release: make this WG's global writes visible device-wide
  if (wg == 0) {
    if (threadIdx.x > 0 && threadIdx.x < NWG) {
      while (__hip_atomic_load(&flags[threadIdx.x * 32], __ATOMIC_ACQUIRE, __HIP_MEMORY_SCOPE_AGENT) < ep)
        __builtin_amdgcn_s_sleep(2);
    }
    __syncthreads();
    if (threadIdx.x == 0)
      __hip_atomic_store(gen, ep, __ATOMIC_RELEASE, __HIP_MEMORY_SCOPE_AGENT);
  } else {
    if (threadIdx.x == 0) {
      __hip_atomic_store(&flags[wg * 32], ep, __ATOMIC_RELEASE, __HIP_MEMORY_SCOPE_AGENT);
      while (__hip_atomic_load(gen, __ATOMIC_ACQUIRE, __HIP_MEMORY_SCOPE_AGENT) < ep)
        __builtin_amdgcn_s_sleep(2);
    }
    __syncthreads();
  }
  __threadfence();  // acquire side for all lanes
}

__global__ void init_ws(float* ws) {
  int tid = threadIdx.x;
  for (int i = tid; i < H; i += 1024) ws[WS_H + i] = 0.f;  // h0 = 0
  int* gen = (int*)(ws + WS_GEN);
  int* flags = (int*)(ws + WS_FLAGS);
  if (tid == 0) *gen = 0;
  for (int i = tid; i < NWG * 32; i += 1024) flags[i] = 0;
}

// ---------------- one-time P = W_ih @ input^T  ([8192,2048]x[512,2048]^T -> [8192,512])
#define GP_BM 128
#define GP_BN 128
#define GP_BK 32
#define GP_PAD 5   // LDS row stride 37 -> conflict-free column reads
__global__ __launch_bounds__(256) void gemm_P(const float* __restrict__ A,
                                              const float* __restrict__ B,
                                              float* __restrict__ P) {
  __shared__ float As[GP_BM][GP_BK + GP_PAD];
  __shared__ float Bs[GP_BN][GP_BK + GP_PAD];
  const int tid = threadIdx.x;
  const int bm = blockIdx.x, bn = blockIdx.y;
  const int tr = tid >> 4, tc = tid & 15;
  float acc[8][8] = {};
  for (int k0 = 0; k0 < H; k0 += GP_BK) {
    #pragma unroll
    for (int i = 0; i < 4; ++i) {
      int lin = tid + 256 * i;       // 1024 float4 per tile
      int r = lin >> 3, c4 = lin & 7;
      float4 va = *(const float4*)(A + (size_t)(bm * GP_BM + r) * H + k0 + c4 * 4);
      float4 vb = *(const float4*)(B + (size_t)(bn * GP_BN + r) * H + k0 + c4 * 4);
      As[r][c4 * 4 + 0] = va.x; As[r][c4 * 4 + 1] = va.y;
      As[r][c4 * 4 + 2] = va.z; As[r][c4 * 4 + 3] = va.w;
      Bs[r][c4 * 4 + 0] = vb.x; Bs[r][c4 * 4 + 1] = vb.y;
      Bs[r][c4 * 4 + 2] = vb.z; Bs[r][c4 * 4 + 3] = vb.w;
    }
    __syncthreads();
    #pragma unroll 8
    for (int k = 0; k < GP_BK; ++k) {
      float a[8], b[8];
      #pragma unroll
      for (int i = 0; i < 8; ++i) a[i] = As[tr * 8 + i][k];
      #pragma unroll
      for (int j = 0; j < 8; ++j) b[j] = Bs[tc * 8 + j][k];
      #pragma unroll
      for (int i = 0; i < 8; ++i)
        #pragma unroll
        for (int j = 0; j < 8; ++j) acc[i][j] += a[i] * b[j];
    }
    __syncthreads();
  }
  #pragma unroll
  for (int i = 0; i < 8; ++i)
    #pragma unroll
    for (int j4 = 0; j4 < 2; ++j4) {
      float4 v = make_float4(acc[i][j4 * 4], acc[i][j4 * 4 + 1],
                             acc[i][j4 * 4 + 2], acc[i][j4 * 4 + 3]);
      *(float4*)(P + (size_t)(bm * GP_BM + tr * 8 + i) * LSEQ + bn * GP_BN + tc * 8 + j4 * 4) = v;
    }
}

// ---------------- persistent main kernel
template <bool USE_P>
__global__ __launch_bounds__(TPB) void attn_rnn_main(
    const float* __restrict__ input, const float* __restrict__ bias_mat,
    const float* __restrict__ conv_w, const float* __restrict__ conv_b,
    const float* __restrict__ fc1_w, const float* __restrict__ fc1_b,
    const float* __restrict__ w_ih, const float* __restrict__ b_ih,
    const float* __restrict__ w_hh, const float* __restrict__ b_hh,
    const int* __restrict__ seq_len,
    float* __restrict__ out, float* __restrict__ ws)
{
  const int wg   = blockIdx.x;
  const int tid  = threadIdx.x;
  const int lane = tid & 63;
  const int wv   = tid >> 6;   // 0..7

  float* uaG   = ws + WS_UA;
  float* xG    = ws + WS_X;
  float* hG    = ws + WS_H;
  int*   genp  = (int*)(ws + WS_GEN);
  int*   flags = (int*)(ws + WS_FLAGS);
  const float* P = ws + WS_P;

  __shared__ float h_lds[H];
  __shared__ float x_lds[H];
  __shared__ float attn_lds[LSEQ];
  __shared__ float ua_lds[LSEQ];
  __shared__ float b_lds[LSEQ];
  __shared__ float g_lds[RPW];
  __shared__ float red8[8];
  __shared__ float red88[64];
  __shared__ float sc[2];
  __shared__ float c_state[UPW];

  const int r_local = tid >> 4;       // 0..31 (gate row within WG)
  const int kg      = tid & 15;       // 0..15 (k-group)
  const int gt      = r_local >> 3;   // gate type i,f,g,o
  const int u       = r_local & 7;    // unit within WG
  const int rg      = gt * H + wg * UPW + u;
  const float brow  = b_ih[rg] + b_hh[rg];
  const float4* whh_row = (const float4*)(w_hh + (size_t)rg * H);
  const float4* wih_row = (const float4*)(w_ih + (size_t)rg * H);
  const float4* p_row   = (const float4*)(P + (size_t)rg * LSEQ);

  if (tid < UPW) c_state[tid] = 0.f;

  int ep = 0;

  // ---- ua[l] = input[l,:]·conv_w + conv_b  (WG owns l = 2wg, 2wg+1) ----
  const float cb = conv_b[0];
  #pragma unroll
  for (int li = 0; li < 2; ++li) {
    int l = wg * 2 + li;
    const float4* row4 = (const float4*)(input + (size_t)l * H);
    const float4* cw4  = (const float4*)conv_w;
    float4 rv = row4[tid], cv = cw4[tid];
    float s = rv.x * cv.x + rv.y * cv.y + rv.z * cv.z + rv.w * cv.w;
    #pragma unroll
    for (int m = 32; m; m >>= 1) s += __shfl_xor(s, m);
    if (lane == 0) red8[wv] = s;
    __syncthreads();
    if (tid == 0) {
      float v = cb;
      #pragma unroll
      for (int q = 0; q < 8; ++q) v += red8[q];
      uaG[l] = v;
    }
    __syncthreads();
  }

  ++ep; flag_barrier(flags, genp, ep, wg);

  // step-invariant per-l terms into LDS
  ua_lds[tid & (LSEQ - 1)] = uaG[tid & (LSEQ - 1)];
  b_lds[tid & (LSEQ - 1)]  = bias_mat[tid & (LSEQ - 1)];
  __syncthreads();

  const int S = seq_len[0];
  const float fb = fc1_b[0];

  for (int t = 0; t < S; ++t) {
    // ---- h -> LDS, w_a = h·fc1_w + fc1_b ----
    float4 hv4 = *(const float4*)(hG + tid * 4);
    float4 fw4 = *(const float4*)(fc1_w + tid * 4);
    *(float4*)(h_lds + tid * 4) = hv4;
    float s = hv4.x * fw4.x + hv4.y * fw4.y + hv4.z * fw4.z + hv4.w * fw4.w;
    #pragma unroll
    for (int m = 32; m; m >>= 1) s += __shfl_xor(s, m);
    if (lane == 0) red8[wv] = s;
    __syncthreads();
    if (tid == 0) {
      float v = fb;
      #pragma unroll
      for (int q = 0; q < 8; ++q) v += red8[q];
      sc[0] = v;
    }
    __syncthreads();
    const float w_a = sc[0];

    // ---- softmax over 512 logits, one per thread ----
    float v0 = ua_lds[tid] + w_a;
    float v = v0 > 0.f ? v0 : 0.01f * v0;   // leaky_relu(0.01)
    v += b_lds[tid];
    float mx = v;
    #pragma unroll
    for (int m = 32; m; m >>= 1) mx = fmaxf(mx, __shfl_xor(mx, m));
    if (lane == 0) red8[wv] = mx;
    __syncthreads();
    if (tid == 0) {
      float q0 = red8[0];
      #pragma unroll
      for (int q = 1; q < 8; ++q) q0 = fmaxf(q0, red8[q]);
      sc[0] = q0;
    }
    __syncthreads();
    mx = sc[0];
    float e = __expf(v - mx);
    attn_lds[tid] = e;
    float se = e;
    #pragma unroll
    for (int m = 32; m; m >>= 1) se += __shfl_xor(se, m);
    if (lane == 0) red8[wv] = se;
    __syncthreads();
    if (tid == 0) {
      float q0 = 0.f;
      #pragma unroll
      for (int q = 0; q < 8; ++q) q0 += red8[q];
      sc[1] = 1.f / q0;
    }
    __syncthreads();
    const float inv = sc[1];

    if constexpr (USE_P) {
      // ---- gates row: whh·h + inv * (P_row · e) ----
      float4 pb[8];
      #pragma unroll
      for (int m = 0; m < 8; ++m) pb[m] = p_row[kg + KG * m];   // issued early

      float acc = 0.f;
      #pragma unroll 8
      for (int m = 0; m < 32; ++m) {
        float4 wv4 = whh_row[kg + KG * m];
        int k = kg * 4 + 64 * m;
        acc += wv4.x * h_lds[k] + wv4.y * h_lds[k + 1] + wv4.z * h_lds[k + 2] + wv4.w * h_lds[k + 3];
      }
      float accp = 0.f;
      #pragma unroll
      for (int m = 0; m < 8; ++m) {
        int l = kg * 4 + 64 * m;
        float4 pv = pb[m];
        accp += pv.x * attn_lds[l] + pv.y * attn_lds[l + 1] + pv.z * attn_lds[l + 2] + pv.w * attn_lds[l + 3];
      }
      acc += accp * inv;
      acc += __shfl_xor(acc, 1);
      acc += __shfl_xor(acc, 2);
      acc += __shfl_xor(acc, 4);
      acc += __shfl_xor(acc, 8);
      if (kg == 0) g_lds[r_local] = acc + brow;
      __syncthreads();

      if (tid < UPW) {
        float iv = g_lds[tid], fv = g_lds[8 + tid], gv = g_lds[16 + tid], ov = g_lds[24 + tid];
        float c_new = sigmoidf_(fv) * c_state[tid] + sigmoidf_(iv) * tanhf(gv);
        float h_new = sigmoidf_(ov) * tanhf(c_new);
        c_state[tid] = c_new;
        hG[wg * UPW + tid] = h_new;
        out[(size_t)t * H + wg * UPW + tid] = h_new;
      }
      ++ep; flag_barrier(flags, genp, ep, wg);
    } else {
      // ---- fallback: explicit x with second barrier ----
      const int j0 = wg * UPW;
      float e_l = attn_lds[tid];
      const float4* r4 = (const float4*)(input + (size_t)tid * H + j0);
      float4 ia = r4[0], ib = r4[1];
      float p[8] = {e_l * ia.x, e_l * ia.y, e_l * ia.z, e_l * ia.w,
                    e_l * ib.x, e_l * ib.y, e_l * ib.z, e_l * ib.w};
      #pragma unroll
      for (int jj = 0; jj < 8; ++jj) {
        float v2 = p[jj];
        #pragma unroll
        for (int m = 32; m; m >>= 1) v2 += __shfl_xor(v2, m);
        if (lane == 0) red88[wv * 8 + jj] = v2;
      }
      __syncthreads();
      if (tid < 8) {
        float v2 = 0.f;
        #pragma unroll
        for (int q = 0; q < 8; ++q) v2 += red88[q * 8 + tid];
        xG[j0 + tid] = v2 * inv;
      }
      float acc = 0.f;
      #pragma unroll 8
      for (int m = 0; m < 32; ++m) {
        float4 wv4 = whh_row[kg + KG * m];
        int k = kg * 4 + 64 * m;
        acc += wv4.x * h_lds[k] + wv4.y * h_lds[k + 1] + wv4.z * h_lds[k + 2] + wv4.w * h_lds[k + 3];
      }
      ++ep; flag_barrier(flags, genp, ep, wg);

      float4 xv4 = *(const float4*)(xG + tid * 4);
      *(float4*)(x_lds + tid * 4) = xv4;
      __syncthreads();
      #pragma unroll 8
      for (int m = 0; m < 32; ++m) {
        float4 wv4 = wih_row[kg + KG * m];
        int k = kg * 4 + 64 * m;
        acc += wv4.x * x_lds[k] + wv4.y * x_lds[k + 1] + wv4.z * x_lds[k + 2] + wv4.w * x_lds[k + 3];
      }
      acc += __shfl_xor(acc, 1);
      acc += __shfl_xor(acc, 2);
      acc += __shfl_xor(acc, 4);
      acc += __shfl_xor(acc, 8);
      if (kg == 0) g_lds[r_local] = acc + brow;
      __syncthreads();

      if (tid < UPW) {
        float iv = g_lds[tid], fv = g_lds[8 + tid], gv = g_lds[16 + tid], ov = g_lds[24 + tid];
        float c_new = sigmoidf_(fv) * c_state[tid] + sigmoidf_(iv) * tanhf(gv);
        float h_new = sigmoidf_(ov) * tanhf(c_new);
        c_state[tid] = c_new;
        hG[wg * UPW + tid] = h_new;
        out[(size_t)t * H + wg * UPW + tid] = h_new;
      }
      ++ep; flag_barrier(flags, genp, ep, wg);
    }
  }
}

extern "C" void kernel_launch(void* const* d_in, const int* in_sizes, int n_in,
                              void* d_out, int out_size, void* d_ws, size_t ws_size,
                              hipStream_t stream) {
  const float* input    = (const float*)d_in[0];
  const float* bias_mat = (const float*)d_in[1];
  const float* conv_w   = (const float*)d_in[2];
  const float* conv_b   = (const float*)d_in[3];
  const float* fc1_w    = (const float*)d_in[4];
  const float* fc1_b    = (const float*)d_in[5];
  const float* w_ih     = (const float*)d_in[6];
  const float* b_ih     = (const float*)d_in[7];
  const float* w_hh     = (const float*)d_in[8];
  const float* b_hh     = (const float*)d_in[9];
  const int*   seqp     = (const int*)d_in[10];
  float* out = (float*)d_out;
  float* ws  = (float*)d_ws;

  const bool use_p = (ws_size >= WS_NEED_BYTES);

  hipLaunchKernelGGL(init_ws, dim3(1), dim3(1024), 0, stream, ws);
  if (use_p) {
    hipLaunchKernelGGL(gemm_P, dim3(64, 4), dim3(256), 0, stream, w_ih, input, ws + WS_P);
    hipLaunchKernelGGL(attn_rnn_main<true>, dim3(NWG), dim3(TPB), 0, stream,
                       input, bias_mat, conv_w, conv_b, fc1_w, fc1_b,
                       w_ih, b_ih, w_hh, b_hh, seqp, out, ws);
  } else {
    hipLaunchKernelGGL(attn_rnn_main<false>, dim3(NWG), dim3(TPB), 0, stream,
                       input, bias_mat, conv_w, conv_b, fc1_w, fc1_b,
                       w_ih, b_ih, w_hh, b_hh, seqp, out, ws);
  }
}

// Round 4
// 31927.612 us; speedup vs baseline: 2.4373x; 1.4562x over previous
//
#include <hip/hip_runtime.h>
#include <hip/hip_bf16.h>

#define H     2048
#define LSEQ  512
#define NWG   256
#define TPB   512
#define UPW   8     // hidden units per WG
#define RPW   32    // gate rows per WG
#define KG    16    // k-groups per row

// ws float-index layout
#define WS_UA    0        // 512 floats
#define WS_H     2560     // 2048 floats
#define WS_GEN   4608     // 1 int
#define WS_FLAGS 4640     // 256*32 ints (128B-padded arrival flags)
#define WS_P     16384    // 8192*512 floats = 16 MB
#define WS_NEED_FLOATS (WS_P + (size_t)4 * H * LSEQ)
#define WS_NEED_BYTES  (WS_NEED_FLOATS * 4)

__device__ __forceinline__ float sigmoidf_(float v) { return 1.f / (1.f + __expf(-v)); }

// Grid barrier. CRITICAL: spins are RELAXED (no per-iteration buffer_inv —
// an ACQUIRE spin invalidates the spinner's whole XCD L2 every iteration,
// which was R3's 90us/step). Visibility: writers' __threadfence() release
// (buffer_wbl2, keeps clean lines) pushes data to MALL before the RELEASE
// flag store; readers re-sync caches ONCE via the trailing __threadfence().
__device__ __forceinline__ void flag_barrier(int* flags, int* gen, int ep, int wg) {
  __syncthreads();
  __threadfence();  // release: push h/out writes toward coherence point
  if (wg == 0) {
    if (threadIdx.x > 0 && threadIdx.x < NWG) {
      while (__hip_atomic_load(&flags[threadIdx.x * 32], __ATOMIC_RELAXED, __HIP_MEMORY_SCOPE_AGENT) < ep)
        __builtin_amdgcn_s_sleep(2);
    }
    __syncthreads();
    if (threadIdx.x == 0)
      __hip_atomic_store(gen, ep, __ATOMIC_RELEASE, __HIP_MEMORY_SCOPE_AGENT);
  } else {
    if (threadIdx.x == 0) {
      __hip_atomic_store(&flags[wg * 32], ep, __ATOMIC_RELEASE, __HIP_MEMORY_SCOPE_AGENT);
      while (__hip_atomic_load(gen, __ATOMIC_RELAXED, __HIP_MEMORY_SCOPE_AGENT) < ep)
        __builtin_amdgcn_s_sleep(2);
    }
    __syncthreads();
  }
  __threadfence();  // acquire: one L2 inv per CU per step (weights are in regs -> immune)
}

__global__ void init_ws(float* ws) {
  int tid = threadIdx.x;
  for (int i = tid; i < H; i += 1024) ws[WS_H + i] = 0.f;  // h0 = 0
  int* gen = (int*)(ws + WS_GEN);
  int* flags = (int*)(ws + WS_FLAGS);
  if (tid == 0) *gen = 0;
  for (int i = tid; i < NWG * 32; i += 1024) flags[i] = 0;
}

// ---------------- one-time P = W_ih @ input^T  ([8192,2048]x[512,2048]^T -> [8192,512])
#define GP_BM 128
#define GP_BN 128
#define GP_BK 32
#define GP_PAD 5
__global__ __launch_bounds__(256) void gemm_P(const float* __restrict__ A,
                                              const float* __restrict__ B,
                                              float* __restrict__ P) {
  __shared__ float As[GP_BM][GP_BK + GP_PAD];
  __shared__ float Bs[GP_BN][GP_BK + GP_PAD];
  const int tid = threadIdx.x;
  const int bm = blockIdx.x, bn = blockIdx.y;
  const int tr = tid >> 4, tc = tid & 15;
  float acc[8][8] = {};
  for (int k0 = 0; k0 < H; k0 += GP_BK) {
    #pragma unroll
    for (int i = 0; i < 4; ++i) {
      int lin = tid + 256 * i;
      int r = lin >> 3, c4 = lin & 7;
      float4 va = *(const float4*)(A + (size_t)(bm * GP_BM + r) * H + k0 + c4 * 4);
      float4 vb = *(const float4*)(B + (size_t)(bn * GP_BN + r) * H + k0 + c4 * 4);
      As[r][c4 * 4 + 0] = va.x; As[r][c4 * 4 + 1] = va.y;
      As[r][c4 * 4 + 2] = va.z; As[r][c4 * 4 + 3] = va.w;
      Bs[r][c4 * 4 + 0] = vb.x; Bs[r][c4 * 4 + 1] = vb.y;
      Bs[r][c4 * 4 + 2] = vb.z; Bs[r][c4 * 4 + 3] = vb.w;
    }
    __syncthreads();
    #pragma unroll 8
    for (int k = 0; k < GP_BK; ++k) {
      float a[8], b[8];
      #pragma unroll
      for (int i = 0; i < 8; ++i) a[i] = As[tr * 8 + i][k];
      #pragma unroll
      for (int j = 0; j < 8; ++j) b[j] = Bs[tc * 8 + j][k];
      #pragma unroll
      for (int i = 0; i < 8; ++i)
        #pragma unroll
        for (int j = 0; j < 8; ++j) acc[i][j] += a[i] * b[j];
    }
    __syncthreads();
  }
  #pragma unroll
  for (int i = 0; i < 8; ++i)
    #pragma unroll
    for (int j4 = 0; j4 < 2; ++j4) {
      float4 v = make_float4(acc[i][j4 * 4], acc[i][j4 * 4 + 1],
                             acc[i][j4 * 4 + 2], acc[i][j4 * 4 + 3]);
      *(float4*)(P + (size_t)(bm * GP_BM + tr * 8 + i) * LSEQ + bn * GP_BN + tc * 8 + j4 * 4) = v;
    }
}

// ---------------- persistent main kernel, weights register-resident
__global__ __launch_bounds__(TPB, 2) void attn_rnn_main(
    const float* __restrict__ input, const float* __restrict__ bias_mat,
    const float* __restrict__ conv_w, const float* __restrict__ conv_b,
    const float* __restrict__ fc1_w, const float* __restrict__ fc1_b,
    const float* __restrict__ w_hh, const float* __restrict__ b_ih,
    const float* __restrict__ b_hh,
    const int* __restrict__ seq_len,
    float* __restrict__ out, float* __restrict__ ws)
{
  const int wg   = blockIdx.x;
  const int tid  = threadIdx.x;
  const int lane = tid & 63;
  const int wv   = tid >> 6;   // 0..7

  float* uaG   = ws + WS_UA;
  float* hG    = ws + WS_H;
  int*   genp  = (int*)(ws + WS_GEN);
  int*   flags = (int*)(ws + WS_FLAGS);
  const float* P = ws + WS_P;

  __shared__ float h_lds[H];
  __shared__ float attn_lds[LSEQ];
  __shared__ float ua_lds[LSEQ];
  __shared__ float b_lds[LSEQ];
  __shared__ float g_lds[RPW];
  __shared__ float red8[8];
  __shared__ float sc[2];
  __shared__ float c_state[UPW];

  const int r_local = tid >> 4;       // 0..31 (gate row within WG)
  const int kg      = tid & 15;       // 0..15 (k-group)
  const int gt      = r_local >> 3;   // gate type i,f,g,o
  const int u       = r_local & 7;    // unit within WG
  const int rg      = gt * H + wg * UPW + u;
  const float brow  = b_ih[rg] + b_hh[rg];
  const float4* whh_row = (const float4*)(w_hh + (size_t)rg * H);
  const float4* p_row   = (const float4*)(P + (size_t)rg * LSEQ);

  // ---- register-resident weights (statically indexed -> stays in VGPRs) ----
  float4 wreg[32];
  #pragma unroll
  for (int m = 0; m < 32; ++m) wreg[m] = whh_row[kg + KG * m];
  float4 preg[8];
  #pragma unroll
  for (int m = 0; m < 8; ++m) preg[m] = p_row[kg + KG * m];
  const float4 fw4 = ((const float4*)fc1_w)[tid];

  if (tid < UPW) c_state[tid] = 0.f;

  int ep = 0;

  // ---- ua[l] = input[l,:]·conv_w + conv_b  (WG owns l = 2wg, 2wg+1) ----
  const float cb = conv_b[0];
  #pragma unroll
  for (int li = 0; li < 2; ++li) {
    int l = wg * 2 + li;
    const float4* row4 = (const float4*)(input + (size_t)l * H);
    const float4* cw4  = (const float4*)conv_w;
    float4 rv = row4[tid], cv = cw4[tid];
    float s = rv.x * cv.x + rv.y * cv.y + rv.z * cv.z + rv.w * cv.w;
    #pragma unroll
    for (int m = 32; m; m >>= 1) s += __shfl_xor(s, m);
    if (lane == 0) red8[wv] = s;
    __syncthreads();
    if (tid == 0) {
      float v = cb;
      #pragma unroll
      for (int q = 0; q < 8; ++q) v += red8[q];
      uaG[l] = v;
    }
    __syncthreads();
  }

  ++ep; flag_barrier(flags, genp, ep, wg);

  // step-invariant per-l terms into LDS (survive the per-step L2 inv)
  ua_lds[tid & (LSEQ - 1)] = uaG[tid & (LSEQ - 1)];
  b_lds[tid & (LSEQ - 1)]  = bias_mat[tid & (LSEQ - 1)];
  __syncthreads();

  const int S = seq_len[0];
  const float fb = fc1_b[0];

  for (int t = 0; t < S; ++t) {
    // ---- h -> LDS, w_a = h·fc1_w + fc1_b ----
    float4 hv4 = *(const float4*)(hG + tid * 4);
    *(float4*)(h_lds + tid * 4) = hv4;
    float s = hv4.x * fw4.x + hv4.y * fw4.y + hv4.z * fw4.z + hv4.w * fw4.w;
    #pragma unroll
    for (int m = 32; m; m >>= 1) s += __shfl_xor(s, m);
    if (lane == 0) red8[wv] = s;
    __syncthreads();
    if (tid == 0) {
      float v = fb;
      #pragma unroll
      for (int q = 0; q < 8; ++q) v += red8[q];
      sc[0] = v;
    }
    __syncthreads();
    const float w_a = sc[0];

    // ---- softmax over 512 logits, one per thread ----
    float v0 = ua_lds[tid] + w_a;
    float v = v0 > 0.f ? v0 : 0.01f * v0;   // leaky_relu(0.01)
    v += b_lds[tid];
    float mx = v;
    #pragma unroll
    for (int m = 32; m; m >>= 1) mx = fmaxf(mx, __shfl_xor(mx, m));
    if (lane == 0) red8[wv] = mx;
    __syncthreads();
    if (tid == 0) {
      float q0 = red8[0];
      #pragma unroll
      for (int q = 1; q < 8; ++q) q0 = fmaxf(q0, red8[q]);
      sc[0] = q0;
    }
    __syncthreads();
    mx = sc[0];
    float e = __expf(v - mx);
    attn_lds[tid] = e;
    float se = e;
    #pragma unroll
    for (int m = 32; m; m >>= 1) se += __shfl_xor(se, m);
    if (lane == 0) red8[wv] = se;
    __syncthreads();
    if (tid == 0) {
      float q0 = 0.f;
      #pragma unroll
      for (int q = 0; q < 8; ++q) q0 += red8[q];
      sc[1] = 1.f / q0;
    }
    __syncthreads();
    const float inv = sc[1];

    // ---- gates row: whh·h + inv * (P_row · e), all weights from registers ----
    float acc = 0.f;
    #pragma unroll
    for (int m = 0; m < 32; ++m) {
      const float4 wv4 = wreg[m];
      const int k = kg * 4 + 64 * m;
      acc += wv4.x * h_lds[k] + wv4.y * h_lds[k + 1] + wv4.z * h_lds[k + 2] + wv4.w * h_lds[k + 3];
    }
    float accp = 0.f;
    #pragma unroll
    for (int m = 0; m < 8; ++m) {
      const float4 pv = preg[m];
      const int l = kg * 4 + 64 * m;
      accp += pv.x * attn_lds[l] + pv.y * attn_lds[l + 1] + pv.z * attn_lds[l + 2] + pv.w * attn_lds[l + 3];
    }
    acc += accp * inv;
    acc += __shfl_xor(acc, 1);
    acc += __shfl_xor(acc, 2);
    acc += __shfl_xor(acc, 4);
    acc += __shfl_xor(acc, 8);
    if (kg == 0) g_lds[r_local] = acc + brow;
    __syncthreads();

    if (tid < UPW) {
      float iv = g_lds[tid], fv = g_lds[8 + tid], gv = g_lds[16 + tid], ov = g_lds[24 + tid];
      float c_new = sigmoidf_(fv) * c_state[tid] + sigmoidf_(iv) * tanhf(gv);
      float h_new = sigmoidf_(ov) * tanhf(c_new);
      c_state[tid] = c_new;
      hG[wg * UPW + tid] = h_new;
      out[(size_t)t * H + wg * UPW + tid] = h_new;
    }
    ++ep; flag_barrier(flags, genp, ep, wg);
  }
}

extern "C" void kernel_launch(void* const* d_in, const int* in_sizes, int n_in,
                              void* d_out, int out_size, void* d_ws, size_t ws_size,
                              hipStream_t stream) {
  const float* input    = (const float*)d_in[0];
  const float* bias_mat = (const float*)d_in[1];
  const float* conv_w   = (const float*)d_in[2];
  const float* conv_b   = (const float*)d_in[3];
  const float* fc1_w    = (const float*)d_in[4];
  const float* fc1_b    = (const float*)d_in[5];
  const float* w_ih     = (const float*)d_in[6];
  const float* b_ih     = (const float*)d_in[7];
  const float* w_hh     = (const float*)d_in[8];
  const float* b_hh     = (const float*)d_in[9];
  const int*   seqp     = (const int*)d_in[10];
  float* out = (float*)d_out;
  float* ws  = (float*)d_ws;

  hipLaunchKernelGGL(init_ws, dim3(1), dim3(1024), 0, stream, ws);
  hipLaunchKernelGGL(gemm_P, dim3(64, 4), dim3(256), 0, stream, w_ih, input, ws + WS_P);
  hipLaunchKernelGGL(attn_rnn_main, dim3(NWG), dim3(TPB), 0, stream,
                     input, bias_mat, conv_w, conv_b, fc1_w, fc1_b,
                     w_hh, b_ih, b_hh, seqp, out, ws);
}

// Round 6
// 4324.871 us; speedup vs baseline: 17.9927x; 7.3823x over previous
//
#include <hip/hip_runtime.h>
#include <hip/hip_bf16.h>

#define H     2048
#define LSEQ  512
#define NWG   256
#define TPB   512
#define UPW   8     // hidden units per WG
#define RPW   32    // gate rows per WG
#define KG    16    // k-groups per row

// ws float-index layout
#define WS_UA    0        // 512 floats
#define WS_H     2560     // 2048 floats
#define WS_GEN   4608     // 1 int
#define WS_FLAGS 4640     // 256*32 ints (128B-padded arrival flags)
#define WS_P     16384    // 8192*512 floats = 16 MB
#define WS_NEED_FLOATS (WS_P + (size_t)4 * H * LSEQ)
#define WS_NEED_BYTES  (WS_NEED_FLOATS * 4)

#define AT_LD(p)    __hip_atomic_load((p),  __ATOMIC_RELAXED, __HIP_MEMORY_SCOPE_SYSTEM)
#define AT_ST(p, v) __hip_atomic_store((p), (v), __ATOMIC_RELAXED, __HIP_MEMORY_SCOPE_SYSTEM)

__device__ __forceinline__ float sigmoidf_(float v) { return 1.f / (1.f + __expf(-v)); }

// Zero-fence grid barrier. All visibility via system-scope (sc0 sc1) atomics
// served at the MALL coherence point. NO __threadfence anywhere in the loop:
// an agent/system fence emits buffer_inv, which flushes the XCD L2 and forces
// the 80 MB/step weight set to re-stream from MALL (R4's 60us/step). The one
// RELEASE store only writes back dirty lines (clean weight lines survive).
__device__ __forceinline__ void flag_barrier(int* flags, int* gen, int ep, int wg) {
  __syncthreads();   // also a compiler memory barrier
  if (wg == 0) {
    if (threadIdx.x > 0 && threadIdx.x < NWG) {
      while (AT_LD(&flags[threadIdx.x * 32]) < ep)
        __builtin_amdgcn_s_sleep(2);
    }
    __syncthreads();
    if (threadIdx.x == 0)
      __hip_atomic_store(gen, ep, __ATOMIC_RELEASE, __HIP_MEMORY_SCOPE_SYSTEM);
  } else {
    if (threadIdx.x == 0) {
      // RELEASE: orders this WG's h-stores (already write-through) before flag
      __hip_atomic_store(&flags[wg * 32], ep, __ATOMIC_RELEASE, __HIP_MEMORY_SCOPE_SYSTEM);
      while (AT_LD(gen) < ep)
        __builtin_amdgcn_s_sleep(2);
    }
    __syncthreads();
  }
}

__global__ void init_ws(float* ws) {
  int tid = threadIdx.x;
  for (int i = tid; i < H; i += 1024) ws[WS_H + i] = 0.f;  // h0 = 0
  int* gen = (int*)(ws + WS_GEN);
  int* flags = (int*)(ws + WS_FLAGS);
  if (tid == 0) *gen = 0;
  for (int i = tid; i < NWG * 32; i += 1024) flags[i] = 0;
}

// ---------------- one-time P = W_ih @ input^T  ([8192,2048]x[512,2048]^T -> [8192,512])
#define GP_BM 128
#define GP_BN 128
#define GP_BK 32
#define GP_PAD 5
__global__ __launch_bounds__(256) void gemm_P(const float* __restrict__ A,
                                              const float* __restrict__ B,
                                              float* __restrict__ P) {
  __shared__ float As[GP_BM][GP_BK + GP_PAD];
  __shared__ float Bs[GP_BN][GP_BK + GP_PAD];
  const int tid = threadIdx.x;
  const int bm = blockIdx.x, bn = blockIdx.y;
  const int tr = tid >> 4, tc = tid & 15;
  float acc[8][8] = {};
  for (int k0 = 0; k0 < H; k0 += GP_BK) {
    #pragma unroll
    for (int i = 0; i < 4; ++i) {
      int lin = tid + 256 * i;
      int r = lin >> 3, c4 = lin & 7;
      float4 va = *(const float4*)(A + (size_t)(bm * GP_BM + r) * H + k0 + c4 * 4);
      float4 vb = *(const float4*)(B + (size_t)(bn * GP_BN + r) * H + k0 + c4 * 4);
      As[r][c4 * 4 + 0] = va.x; As[r][c4 * 4 + 1] = va.y;
      As[r][c4 * 4 + 2] = va.z; As[r][c4 * 4 + 3] = va.w;
      Bs[r][c4 * 4 + 0] = vb.x; Bs[r][c4 * 4 + 1] = vb.y;
      Bs[r][c4 * 4 + 2] = vb.z; Bs[r][c4 * 4 + 3] = vb.w;
    }
    __syncthreads();
    #pragma unroll 8
    for (int k = 0; k < GP_BK; ++k) {
      float a[8], b[8];
      #pragma unroll
      for (int i = 0; i < 8; ++i) a[i] = As[tr * 8 + i][k];
      #pragma unroll
      for (int j = 0; j < 8; ++j) b[j] = Bs[tc * 8 + j][k];
      #pragma unroll
      for (int i = 0; i < 8; ++i)
        #pragma unroll
        for (int j = 0; j < 8; ++j) acc[i][j] += a[i] * b[j];
    }
    __syncthreads();
  }
  #pragma unroll
  for (int i = 0; i < 8; ++i)
    #pragma unroll
    for (int j4 = 0; j4 < 2; ++j4) {
      float4 v = make_float4(acc[i][j4 * 4], acc[i][j4 * 4 + 1],
                             acc[i][j4 * 4 + 2], acc[i][j4 * 4 + 3]);
      *(float4*)(P + (size_t)(bm * GP_BM + tr * 8 + i) * LSEQ + bn * GP_BN + tc * 8 + j4 * 4) = v;
    }
}

// ---------------- persistent main kernel
__global__ __launch_bounds__(TPB, 2) void attn_rnn_main(
    const float* __restrict__ input, const float* __restrict__ bias_mat,
    const float* __restrict__ conv_w, const float* __restrict__ conv_b,
    const float* __restrict__ fc1_w, const float* __restrict__ fc1_b,
    const float* __restrict__ w_hh, const float* __restrict__ b_ih,
    const float* __restrict__ b_hh,
    const int* __restrict__ seq_len,
    float* __restrict__ out, float* __restrict__ ws)
{
  const int wg   = blockIdx.x;
  const int tid  = threadIdx.x;
  const int lane = tid & 63;
  const int wv   = tid >> 6;   // 0..7

  float* uaG   = ws + WS_UA;
  float* hG    = ws + WS_H;
  int*   genp  = (int*)(ws + WS_GEN);
  int*   flags = (int*)(ws + WS_FLAGS);
  const float* P = ws + WS_P;

  __shared__ float h_lds[H];
  __shared__ float attn_lds[LSEQ];
  __shared__ float ua_lds[LSEQ];
  __shared__ float b_lds[LSEQ];
  __shared__ float g_lds[RPW];
  __shared__ float red8[8];
  __shared__ float sc[2];
  __shared__ float c_state[UPW];

  const int r_local = tid >> 4;       // 0..31 (gate row within WG)
  const int kg      = tid & 15;       // 0..15 (k-group)
  const int gt      = r_local >> 3;   // gate type i,f,g,o
  const int u       = r_local & 7;    // unit within WG
  const int rg      = gt * H + wg * UPW + u;
  const float brow  = b_ih[rg] + b_hh[rg];
  const float4* whh_row = (const float4*)(w_hh + (size_t)rg * H);
  const float4* p_row   = (const float4*)(P + (size_t)rg * LSEQ);

  // ---- W_hh slice register-resident; asm pin blocks rematerialization ----
  float4 wreg[32];
  #pragma unroll
  for (int m = 0; m < 32; ++m) wreg[m] = whh_row[kg + KG * m];
  #pragma unroll
  for (int m = 0; m < 32; ++m)
    asm volatile("" : "+v"(wreg[m].x), "+v"(wreg[m].y), "+v"(wreg[m].z), "+v"(wreg[m].w));

  const float4 fw4 = ((const float4*)fc1_w)[tid];

  if (tid < UPW) c_state[tid] = 0.f;

  int ep = 0;

  // ---- ua[l] = input[l,:]·conv_w + conv_b  (WG owns l = 2wg, 2wg+1) ----
  const float cb = conv_b[0];
  #pragma unroll
  for (int li = 0; li < 2; ++li) {
    int l = wg * 2 + li;
    const float4* row4 = (const float4*)(input + (size_t)l * H);
    const float4* cw4  = (const float4*)conv_w;
    float4 rv = row4[tid], cv = cw4[tid];
    float s = rv.x * cv.x + rv.y * cv.y + rv.z * cv.z + rv.w * cv.w;
    #pragma unroll
    for (int m = 32; m; m >>= 1) s += __shfl_xor(s, m);
    if (lane == 0) red8[wv] = s;
    __syncthreads();
    if (tid == 0) {
      float v = cb;
      #pragma unroll
      for (int q = 0; q < 8; ++q) v += red8[q];
      AT_ST(&uaG[l], v);   // write-through, coherent at MALL
    }
    __syncthreads();
  }

  ++ep; flag_barrier(flags, genp, ep, wg);

  // step-invariant per-l terms into LDS (ua via coherent loads)
  ua_lds[tid & (LSEQ - 1)] = AT_LD(&uaG[tid & (LSEQ - 1)]);
  b_lds[tid & (LSEQ - 1)]  = bias_mat[tid & (LSEQ - 1)];
  __syncthreads();

  const int S = seq_len[0];
  const float fb = fc1_b[0];

  for (int t = 0; t < S; ++t) {
    // ---- h -> LDS via coherent (sc0 sc1) loads; w_a = h·fc1_w + fc1_b ----
    float4 hv4;
    hv4.x = AT_LD(hG + tid * 4 + 0);
    hv4.y = AT_LD(hG + tid * 4 + 1);
    hv4.z = AT_LD(hG + tid * 4 + 2);
    hv4.w = AT_LD(hG + tid * 4 + 3);
    *(float4*)(h_lds + tid * 4) = hv4;
    float s = hv4.x * fw4.x + hv4.y * fw4.y + hv4.z * fw4.z + hv4.w * fw4.w;
    #pragma unroll
    for (int m = 32; m; m >>= 1) s += __shfl_xor(s, m);
    if (lane == 0) red8[wv] = s;
    __syncthreads();
    if (tid == 0) {
      float v = fb;
      #pragma unroll
      for (int q = 0; q < 8; ++q) v += red8[q];
      sc[0] = v;
    }
    __syncthreads();
    const float w_a = sc[0];

    // ---- softmax over 512 logits, one per thread ----
    float v0 = ua_lds[tid] + w_a;
    float v = v0 > 0.f ? v0 : 0.01f * v0;   // leaky_relu(0.01)
    v += b_lds[tid];
    float mx = v;
    #pragma unroll
    for (int m = 32; m; m >>= 1) mx = fmaxf(mx, __shfl_xor(mx, m));
    if (lane == 0) red8[wv] = mx;
    __syncthreads();
    if (tid == 0) {
      float q0 = red8[0];
      #pragma unroll
      for (int q = 1; q < 8; ++q) q0 = fmaxf(q0, red8[q]);
      sc[0] = q0;
    }
    __syncthreads();
    mx = sc[0];
    float e = __expf(v - mx);
    attn_lds[tid] = e;
    float se = e;
    #pragma unroll
    for (int m = 32; m; m >>= 1) se += __shfl_xor(se, m);
    if (lane == 0) red8[wv] = se;
    __syncthreads();
    if (tid == 0) {
      float q0 = 0.f;
      #pragma unroll
      for (int q = 0; q < 8; ++q) q0 += red8[q];
      sc[1] = 1.f / q0;
    }
    __syncthreads();
    const float inv = sc[1];

    // ---- gates row: whh·h (regs) + inv * (P_row · e) (P streams from hot L2) ----
    float4 pb[8];
    #pragma unroll
    for (int m = 0; m < 8; ++m) pb[m] = p_row[kg + KG * m];

    float acc = 0.f;
    #pragma unroll
    for (int m = 0; m < 32; ++m) {
      const float4 wv4 = wreg[m];
      const int k = kg * 4 + 64 * m;
      acc += wv4.x * h_lds[k] + wv4.y * h_lds[k + 1] + wv4.z * h_lds[k + 2] + wv4.w * h_lds[k + 3];
    }
    float accp = 0.f;
    #pragma unroll
    for (int m = 0; m < 8; ++m) {
      const float4 pv = pb[m];
      const int l = kg * 4 + 64 * m;
      accp += pv.x * attn_lds[l] + pv.y * attn_lds[l + 1] + pv.z * attn_lds[l + 2] + pv.w * attn_lds[l + 3];
    }
    acc += accp * inv;
    acc += __shfl_xor(acc, 1);
    acc += __shfl_xor(acc, 2);
    acc += __shfl_xor(acc, 4);
    acc += __shfl_xor(acc, 8);
    if (kg == 0) g_lds[r_local] = acc + brow;
    __syncthreads();

    if (tid < UPW) {
      float iv = g_lds[tid], fv = g_lds[8 + tid], gv = g_lds[16 + tid], ov = g_lds[24 + tid];
      float c_new = sigmoidf_(fv) * c_state[tid] + sigmoidf_(iv) * tanhf(gv);
      float h_new = sigmoidf_(ov) * tanhf(c_new);
      c_state[tid] = c_new;
      AT_ST(&hG[wg * UPW + tid], h_new);   // write-through to MALL
      out[(size_t)t * H + wg * UPW + tid] = h_new;  // plain cached store
    }
    ++ep; flag_barrier(flags, genp, ep, wg);
  }
}

extern "C" void kernel_launch(void* const* d_in, const int* in_sizes, int n_in,
                              void* d_out, int out_size, void* d_ws, size_t ws_size,
                              hipStream_t stream) {
  const float* input    = (const float*)d_in[0];
  const float* bias_mat = (const float*)d_in[1];
  const float* conv_w   = (const float*)d_in[2];
  const float* conv_b   = (const float*)d_in[3];
  const float* fc1_w    = (const float*)d_in[4];
  const float* fc1_b    = (const float*)d_in[5];
  const float* w_ih     = (const float*)d_in[6];
  const float* b_ih     = (const float*)d_in[7];
  const float* w_hh     = (const float*)d_in[8];
  const float* b_hh     = (const float*)d_in[9];
  const int*   seqp     = (const int*)d_in[10];
  float* out = (float*)d_out;
  float* ws  = (float*)d_ws;

  hipLaunchKernelGGL(init_ws, dim3(1), dim3(1024), 0, stream, ws);
  hipLaunchKernelGGL(gemm_P, dim3(64, 4), dim3(256), 0, stream, w_ih, input, ws + WS_P);
  hipLaunchKernelGGL(attn_rnn_main, dim3(NWG), dim3(TPB), 0, stream,
                     input, bias_mat, conv_w, conv_b, fc1_w, fc1_b,
                     w_hh, b_ih, b_hh, seqp, out, ws);
}